// Round 4
// baseline (109.742 us; speedup 1.0000x reference)
//
#include <hip/hip_runtime.h>

#define NPTS 8192      // H*W
#define BCLS 4         // C
#define NP   6         // B*(C-1) pairs
#define R2   9.0f
#define RAD  3.0f
#define GRD  64
#define NCELL (GRD*GRD)
#define PCAP 2048      // pending-list capacity (overflow -> sweep fallback)
#define LDSK 2048      // LDS kept-center accumulator cap (overflow -> global)

#define ST_U 0u
#define ST_A 1u
#define ST_D 2u

// ---------------------------------------------------------------------------
// R17 = R11 engine verbatim + 4-wide batched LDS loads in ALL window scans.
// Post-mortem R14/R15/R16: every round-machinery change (cheap rescans, fewer
// barriers, barrier-free single-wave tail) was flat-to-worse => the fixed
// point is a minor term. VALUBusy ~29% on active CUs with no HBM traffic =>
// latency-bound. The dynamic-trip scan loops emit ds_read/ds_read/waitcnt per
// candidate (no unroll possible) -> full ~120cy LDS latency exposed PER
// CANDIDATE (m117). Fix: issue 4 candidates' cmb+sps (8 ds_reads) before any
// use, masked tail via index-clamp (load f0 again, contribution masked), and
// load all 4 cellpack range words up front. Identical arithmetic; argmin
// combine applied in f-order so tie-breaks are unchanged; status snapshot
// timing stays monotone-conservative.
// ---------------------------------------------------------------------------
__global__ __launch_bounds__(1024) void k_fused(
    const float* __restrict__ seg, const float* __restrict__ lidar,
    float* __restrict__ sumx, float* __restrict__ sumy, float* __restrict__ cntw,
    float* __restrict__ out)
{
    const int p = blockIdx.x;
    const int b = p / 3, cls = p % 3 + 1;
    const int tid = threadIdx.x, lane = tid & 63, wv = tid >> 6;
    const int base = p * NPTS;

    __shared__ float2 sps[NPTS];                // 64 KB: pixel-space, then grid-space
    __shared__ unsigned int cmb[NPTS];          // 32 KB: pixel<<2 | status (grid)
    __shared__ unsigned int cellpack[NCELL];    // 16 KB: start<<16 | cnt
    __shared__ unsigned short plist[2][PCAP];   //  8 KB: pending lists
    __shared__ float ksx[LDSK], ksy[LDSK], kcn[LDSK];  // 24 KB
    __shared__ int pcnt[2];
    __shared__ unsigned long long ballots[128]; //  1 KB: mask words, later kept words
    __shared__ unsigned int base128[128];       // 512 B
    __shared__ unsigned int wtot[16];
    __shared__ float redbuf[4][16];
    __shared__ float sbminx, sbminy, scell;
    __shared__ int sM, sK;

    float* ok = out + (size_t)2 * NP * NPTS + base;

    // ---- P0: zeroing ----
    for (int k = tid; k < NPTS; k += 1024) { cmb[k] = ST_U; ok[k] = 0.f; }
    {
        float2* oc = (float2*)(out + (size_t)2 * base);
        for (int k = tid; k < NPTS; k += 1024) oc[k] = make_float2(0.f, 0.f);
    }
    for (int k = tid; k < NCELL; k += 1024) cellpack[k] = 0u;
    for (int k = tid; k < LDSK; k += 1024) { ksx[k] = 0.f; ksy[k] = 0.f; kcn[k] = 0.f; }
    if (tid == 0) { pcnt[0] = 0; pcnt[1] = 0; }

    // ---- P1: argmax -> mask ballots; stage lidar into sps (pixel space) ----
    const float* segb = seg + (size_t)b * BCLS * NPTS;
    const float* lx = lidar + (size_t)b * 2 * NPTS;
    const float* ly = lx + NPTS;
    for (int c0 = 0; c0 < 8; ++c0) {
        int n = c0 * 1024 + tid;
        float bv = segb[n];
        int bc = 0;
        #pragma unroll
        for (int c2 = 1; c2 < BCLS; ++c2) {
            float v = segb[c2 * NPTS + n];
            if (v > bv) { bv = v; bc = c2; }   // strict >: first index wins ties
        }
        unsigned long long bal = __ballot(bc == cls);
        if (lane == 0) ballots[c0 * 16 + wv] = bal;
    }
    for (int n = tid; n < NPTS; n += 1024) sps[n] = make_float2(lx[n], ly[n]);
    __syncthreads();
    if (wv == 0) {                              // M = sum of popcounts
        unsigned int s = (unsigned int)__popcll(ballots[2 * lane]) +
                         (unsigned int)__popcll(ballots[2 * lane + 1]);
        for (int d = 1; d < 64; d <<= 1) s += __shfl_xor(s, d, 64);
        if (lane == 0) sM = (int)s;
    }

    // ---- P2: bbox (chunked: thread owns pixels tid*8..tid*8+7) ----
    const unsigned long long mw = ballots[tid >> 3];
    {
        float mnx = 3e38f, mxx = -3e38f, mny = 3e38f, mxy = -3e38f;
        #pragma unroll
        for (int q = 0; q < 8; ++q) {
            int n = tid * 8 + q;
            bool m = (mw >> (((tid & 7) << 3) + q)) & 1ull;
            float2 c = sps[n];
            if (m) {
                mnx = fminf(mnx, c.x); mxx = fmaxf(mxx, c.x);
                mny = fminf(mny, c.y); mxy = fmaxf(mxy, c.y);
            }
        }
        for (int d = 32; d; d >>= 1) {
            mnx = fminf(mnx, __shfl_xor(mnx, d, 64));
            mxx = fmaxf(mxx, __shfl_xor(mxx, d, 64));
            mny = fminf(mny, __shfl_xor(mny, d, 64));
            mxy = fmaxf(mxy, __shfl_xor(mxy, d, 64));
        }
        if (lane == 0) { redbuf[0][wv] = mnx; redbuf[1][wv] = mxx;
                         redbuf[2][wv] = mny; redbuf[3][wv] = mxy; }
    }
    __syncthreads();
    if (tid == 0) {
        float a = redbuf[0][0], b2 = redbuf[1][0], c = redbuf[2][0], d = redbuf[3][0];
        for (int q = 1; q < 16; ++q) {
            a = fminf(a, redbuf[0][q]); b2 = fmaxf(b2, redbuf[1][q]);
            c = fminf(c, redbuf[2][q]); d = fmaxf(d, redbuf[3][q]);
        }
        sbminx = a; sbminy = c;
        scell = fmaxf(2.0f * RAD, fmaxf(b2 - a, d - c) / 63.0f);
    }
    __syncthreads();
    const float bminx = sbminx, bminy = sbminy, inv = 1.0f / scell;
    const int M = sM;

    // ---- P3: grid count / scan / scatter; coords held in regs across scatter ----
    float xq[8], yq[8];
    int cellq[8];
    #pragma unroll
    for (int q = 0; q < 8; ++q) {
        int n = tid * 8 + q;
        bool m = (mw >> (((tid & 7) << 3) + q)) & 1ull;
        float2 c = sps[n];
        xq[q] = c.x; yq[q] = c.y;
        int ix = min(GRD - 1, max(0, (int)((c.x - bminx) * inv)));
        int iy = min(GRD - 1, max(0, (int)((c.y - bminy) * inv)));
        cellq[q] = m ? (iy * GRD + ix) : -1;
        if (m) atomicAdd(&cellpack[iy * GRD + ix], 1u);
    }
    __syncthreads();
    {
        unsigned int c4[4], t4 = 0;
        #pragma unroll
        for (int q = 0; q < 4; ++q) { c4[q] = cellpack[tid * 4 + q]; t4 += c4[q]; }
        unsigned int v = t4;
        for (int d = 1; d < 64; d <<= 1) {
            unsigned int u = __shfl_up(v, d, 64);
            if (lane >= d) v += u;
        }
        if (lane == 63) wtot[wv] = v;
        __syncthreads();
        if (tid == 0) {
            unsigned int acc = 0;
            for (int q = 0; q < 16; ++q) { unsigned int t = wtot[q]; wtot[q] = acc; acc += t; }
        }
        __syncthreads();
        unsigned int excl = wtot[wv] + v - t4;
        #pragma unroll
        for (int q = 0; q < 4; ++q) { cellpack[tid * 4 + q] = excl << 16; excl += c4[q]; }
    }
    __syncthreads();
    #pragma unroll
    for (int q = 0; q < 8; ++q) {
        if (cellq[q] >= 0) {
            unsigned int old = atomicAdd(&cellpack[cellq[q]], 1u);
            unsigned int pos = (old >> 16) + (old & 0xffffu);
            sps[pos] = make_float2(xq[q], yq[q]);
            cmb[pos] = ((unsigned int)(tid * 8 + q) << 2) | ST_U;
        }
    }   // cellpack now = start<<16 | cnt; sps/cmb now grid-space
    __syncthreads();

    // ---- batched window-scan primitives: 4 candidates' loads issued before
    //      any use; masked tail re-reads f0 (valid addr) with contribution
    //      masked; combine in f-order so semantics (incl. tie-breaks) match.
    #define FLAG1(V, WF, QQ, NI, ME, DEAD, UNDEC)                                 \
    {                                                                             \
        float dx = __fsub_rn((ME).x, (QQ).x), dy = __fsub_rn((ME).y, (QQ).y);     \
        float d2 = __fadd_rn(__fmul_rn(dx, dx), __fmul_rn(dy, dy));               \
        bool in = (V) & (d2 < R2) & ((int)((WF) >> 2) < (NI));                    \
        DEAD  |= in & (((WF) & 3u) == ST_A);                                      \
        UNDEC |= in & (((WF) & 3u) == ST_U);                                      \
    }
    #define BATCH_FLAGS(F0, F1, NI, ME, DEAD, UNDEC)                              \
    for (unsigned int f = (F0); f < (F1); f += 4) {                               \
        unsigned int ff1 = f + 1 < (F1) ? f + 1 : (F0);                           \
        unsigned int ff2 = f + 2 < (F1) ? f + 2 : (F0);                           \
        unsigned int ff3 = f + 3 < (F1) ? f + 3 : (F0);                           \
        unsigned int w0_ = cmb[f],   w1_ = cmb[ff1];                              \
        unsigned int w2_ = cmb[ff2], w3_ = cmb[ff3];                              \
        float2 q0_ = sps[f],   q1_ = sps[ff1];                                    \
        float2 q2_ = sps[ff2], q3_ = sps[ff3];                                    \
        FLAG1(true,         w0_, q0_, NI, ME, DEAD, UNDEC);                       \
        FLAG1(f + 1 < (F1), w1_, q1_, NI, ME, DEAD, UNDEC);                       \
        FLAG1(f + 2 < (F1), w2_, q2_, NI, ME, DEAD, UNDEC);                       \
        FLAG1(f + 3 < (F1), w3_, q3_, NI, ME, DEAD, UNDEC);                       \
    }
    #define SCAN_FLAGS(NI, ME, DEAD, UNDEC)                                       \
    {                                                                             \
        int cx0 = max(0, (int)(((ME).x - RAD - bminx) * inv));                    \
        int cx1 = min(GRD - 1, (int)(((ME).x + RAD - bminx) * inv));              \
        int cy0 = max(0, (int)(((ME).y - RAD - bminy) * inv));                    \
        int cy1 = min(GRD - 1, (int)(((ME).y + RAD - bminy) * inv));              \
        unsigned int wa0 = cellpack[cy0 * GRD + cx0];                             \
        unsigned int wb0 = cellpack[cy0 * GRD + cx1];                             \
        unsigned int wa1 = cellpack[cy1 * GRD + cx0];                             \
        unsigned int wb1 = cellpack[cy1 * GRD + cx1];                             \
        unsigned int f0a = wa0 >> 16, f1a = (wb0 >> 16) + (wb0 & 0xffffu);        \
        unsigned int f0b = wa1 >> 16, f1b = (wb1 >> 16) + (wb1 & 0xffffu);        \
        if (cy1 == cy0) f1b = f0b;               /* single-row window */          \
        DEAD = false; UNDEC = false;                                              \
        BATCH_FLAGS(f0a, f1a, NI, ME, DEAD, UNDEC);                               \
        BATCH_FLAGS(f0b, f1b, NI, ME, DEAD, UNDEC);                               \
    }

    // ---- P4 round 0: full sweep (grid order), wave-ordered pending append ----
    for (int e = tid; e < M; e += 1024) {
        unsigned int w = cmb[e];
        int ni = (int)(w >> 2);
        float2 me = sps[e];
        bool dead, undec;
        SCAN_FLAGS(ni, me, dead, undec);
        if (dead) cmb[e] = (w & ~3u) | ST_D;
        else if (!undec) cmb[e] = (w & ~3u) | ST_A;
        bool pendf = !dead && undec;
        unsigned long long act = __ballot(true);
        unsigned long long bal = __ballot(pendf);
        int leader = __builtin_ctzll(act);
        int cnt = __popcll(bal);
        int wbase = 0;
        if (lane == leader && cnt) wbase = atomicAdd(&pcnt[0], cnt);
        wbase = __shfl(wbase, leader, 64);
        if (pendf) {
            int pos = wbase + __popcll(bal & ((1ull << lane) - 1ull));
            if (pos < PCAP) plist[0][pos] = (unsigned short)e;
        }
    }

    // ---- P4 rounds over compacted pending (proven engine) ----
    int cur = 0;
    for (int round = 0; round < NPTS; ++round) {
        __syncthreads();
        int pc = pcnt[cur];
        if (pc == 0) break;
        if (pc > PCAP) {                        // overflow fallback: full sweeps
            for (;;) {
                bool any = false;
                __syncthreads();
                for (int e = tid; e < M; e += 1024) {
                    unsigned int w = cmb[e];
                    if ((w & 3u) != ST_U) continue;
                    int ni = (int)(w >> 2);
                    float2 me = sps[e];
                    bool dead, undec;
                    SCAN_FLAGS(ni, me, dead, undec);
                    if (dead) cmb[e] = (w & ~3u) | ST_D;
                    else if (!undec) cmb[e] = (w & ~3u) | ST_A;
                    else any = true;
                }
                if (__syncthreads_count(any) == 0) break;
            }
            break;
        }
        if (tid == 0) pcnt[cur ^ 1] = 0;
        __syncthreads();
        for (int idx = tid; idx < pc; idx += 1024) {
            int e = plist[cur][idx];
            unsigned int w = cmb[e];
            int ni = (int)(w >> 2);
            float2 me = sps[e];
            bool dead, undec;
            SCAN_FLAGS(ni, me, dead, undec);
            if (dead) cmb[e] = (w & ~3u) | ST_D;
            else if (!undec) cmb[e] = (w & ~3u) | ST_A;
            bool pendf = !dead && undec;
            unsigned long long act = __ballot(true);
            unsigned long long bal = __ballot(pendf);
            int leader = __builtin_ctzll(act);
            int cnt = __popcll(bal);
            int wbase = 0;
            if (lane == leader && cnt) wbase = atomicAdd(&pcnt[cur ^ 1], cnt);
            wbase = __shfl(wbase, leader, 64);
            if (pendf) {
                int pos = wbase + __popcll(bal & ((1ull << lane) - 1ull));
                if (pos < PCAP) plist[cur ^ 1][pos] = (unsigned short)e;
            }
        }
        cur ^= 1;
    }
    __syncthreads();

    // ---- kept-rank over grid space: ballot bitmask + wave-scanned prefix ----
    for (int k = 0; k < 8; ++k) {
        int e = (k << 10) + tid;
        unsigned long long bal = __ballot((cmb[e] & 3u) == ST_A);  // e>=M stays U
        if (lane == 0) ballots[(k << 4) + wv] = bal;
    }
    __syncthreads();
    if (wv == 0) {
        unsigned int p0 = (unsigned int)__popcll(ballots[2 * lane]);
        unsigned int p1 = (unsigned int)__popcll(ballots[2 * lane + 1]);
        unsigned int s = p0 + p1, v = s;
        for (int d = 1; d < 64; d <<= 1) {
            unsigned int u = __shfl_up(v, d, 64);
            if (lane >= d) v += u;
        }
        base128[2 * lane] = v - s;
        base128[2 * lane + 1] = v - p1;
        if (lane == 63) sK = (int)v;
    }
    __syncthreads();
    #define KRANK(E) ((int)base128[(E) >> 6] +                                    \
                      __popcll(ballots[(E) >> 6] & ((1ull << ((E) & 63)) - 1ull)))
    if (sK > LDSK) {                            // cold fallback prep: zero globals
        for (int k = tid; k < NPTS; k += 1024) {
            sumx[base + k] = 0.f; sumy[base + k] = 0.f; cntw[base + k] = 0.f;
        }
        __syncthreads();
    }

    // ---- P5: assignment + LDS accumulation (batched branchless argmin) ----
    #define ARG1(V, WF, QQ, ME, BD, BE, BN, FIDX)                                 \
    {                                                                             \
        float dx = __fsub_rn((ME).x, (QQ).x), dy = __fsub_rn((ME).y, (QQ).y);     \
        float d2 = __fadd_rn(__fmul_rn(dx, dx), __fmul_rn(dy, dy));               \
        int nf = (int)((WF) >> 2);                                                \
        bool better = (V) & (((WF) & 3u) == ST_A) &                               \
                      ((d2 < BD) | ((d2 == BD) & (nf < BN)));                     \
        BD = better ? d2 : BD;                                                    \
        BE = better ? (int)(FIDX) : BE;                                           \
        BN = better ? nf : BN;                                                    \
    }
    #define BATCH_ARGMIN(F0, F1, ME, BD, BE, BN)                                  \
    for (unsigned int f = (F0); f < (F1); f += 4) {                               \
        unsigned int ff1 = f + 1 < (F1) ? f + 1 : (F0);                           \
        unsigned int ff2 = f + 2 < (F1) ? f + 2 : (F0);                           \
        unsigned int ff3 = f + 3 < (F1) ? f + 3 : (F0);                           \
        unsigned int w0_ = cmb[f],   w1_ = cmb[ff1];                              \
        unsigned int w2_ = cmb[ff2], w3_ = cmb[ff3];                              \
        float2 q0_ = sps[f],   q1_ = sps[ff1];                                    \
        float2 q2_ = sps[ff2], q3_ = sps[ff3];                                    \
        ARG1(true,         w0_, q0_, ME, BD, BE, BN, f);                          \
        ARG1(f + 1 < (F1), w1_, q1_, ME, BD, BE, BN, ff1);                        \
        ARG1(f + 2 < (F1), w2_, q2_, ME, BD, BE, BN, ff2);                        \
        ARG1(f + 3 < (F1), w3_, q3_, ME, BD, BE, BN, ff3);                        \
    }
    for (int e = tid; e < M; e += 1024) {
        unsigned int w = cmb[e];
        float2 me = sps[e];
        int be;
        if ((w & 3u) == ST_A) {
            be = e;                              // self: unique d2 = 0
        } else {
            int cx0 = max(0, (int)((me.x - RAD - bminx) * inv));
            int cx1 = min(GRD - 1, (int)((me.x + RAD - bminx) * inv));
            int cy0 = max(0, (int)((me.y - RAD - bminy) * inv));
            int cy1 = min(GRD - 1, (int)((me.y + RAD - bminy) * inv));
            unsigned int wa0 = cellpack[cy0 * GRD + cx0];
            unsigned int wb0 = cellpack[cy0 * GRD + cx1];
            unsigned int wa1 = cellpack[cy1 * GRD + cx0];
            unsigned int wb1 = cellpack[cy1 * GRD + cx1];
            unsigned int f0a = wa0 >> 16, f1a = (wb0 >> 16) + (wb0 & 0xffffu);
            unsigned int f0b = wa1 >> 16, f1b = (wb1 >> 16) + (wb1 & 0xffffu);
            if (cy1 == cy0) f1b = f0b;
            float bd = 3e38f;
            be = -1;
            int bn = 1 << 30;
            BATCH_ARGMIN(f0a, f1a, me, bd, be, bn);
            BATCH_ARGMIN(f0b, f1b, me, bd, be, bn);
            if (be < 0) continue;                // impossible when M > 0
        }
        int r = KRANK(be);
        if (r < LDSK) {
            atomicAdd(&ksx[r], me.x);
            atomicAdd(&ksy[r], me.y);
            atomicAdd(&kcn[r], 1.0f);
        } else {                                 // cold fallback: global by grid pos
            atomicAdd(&sumx[base + be], me.x);
            atomicAdd(&sumy[base + be], me.y);
            atomicAdd(&cntw[base + be], 1.0f);
        }
    }
    __syncthreads();

    // ---- P6: kept candidates overwrite the zeroed output slice ----
    for (int e = tid; e < M; e += 1024) {
        unsigned int w = cmb[e];
        if ((w & 3u) != ST_A) continue;
        int n = (int)(w >> 2);
        int r = KRANK(e);
        float sx, sy, c;
        if (r < LDSK) { sx = ksx[r]; sy = ksy[r]; c = kcn[r]; }
        else { sx = sumx[base + e]; sy = sumy[base + e]; c = cntw[base + e]; }
        out[2 * (base + n)]     = sx / c;        // c >= 1 (self-assign)
        out[2 * (base + n) + 1] = sy / c;
        ok[n] = 1.0f;
    }
}

// ---------------------------------------------------------------------------
extern "C" void kernel_launch(void* const* d_in, const int* in_sizes, int n_in,
                              void* d_out, int out_size, void* d_ws, size_t ws_size,
                              hipStream_t stream) {
    const float* seg   = (const float*)d_in[0];   // [B,C,H,W] f32
    const float* lidar = (const float*)d_in[1];   // [B,2,H,W] f32
    float* out = (float*)d_out;

    const size_t A = (size_t)NP * NPTS;           // 49152
    float* sumx = (float*)d_ws;                   // 4A (fallback only)
    float* sumy = sumx + A;                       // 4A
    float* cntw = sumy + A;                       // 4A

    k_fused<<<NP, 1024, 0, stream>>>(seg, lidar, sumx, sumy, cntw, out);
}

// Round 5
// 105.922 us; speedup vs baseline: 1.0361x; 1.0361x over previous
//
#include <hip/hip_runtime.h>

#define NPTS 8192      // H*W
#define BCLS 4         // C
#define NP   6         // B*(C-1) pairs
#define R2   9.0f
#define RAD  3.0f
#define GRD  64
#define NCELL (GRD*GRD)
#define PCAP 2048      // pending-list capacity (overflow -> sweep fallback)
#define LDSK 2048      // LDS kept-center accumulator cap (multi-pass if exceeded)
#define KBLK 64        // front kernel blocks
#define KTHR 256       // front kernel threads (KBLK*KTHR == B*NPTS)

#define ST_U 0u
#define ST_A 1u
#define ST_D 2u

// ---------------------------------------------------------------------------
// R18: two-kernel split. Post-mortem R14-R17: all NMS-engine micro-variants
// (rotating counters, blocker lists, single-wave tail, batched loads) were
// flat-to-worse => the engine is not where the time is claimed to be. The
// untouched term is the pixel-space front half on 6 CUs: redundant argmax
// (3 same-b blocks re-read the same 128KB seg slice), 8192-pixel P0/P2/P3
// loops, 96KB/block global zeroing. K1 (64x256, wide) does argmax once,
// compacts (x,y,n) per pair into deterministic per-block slabs + counts,
// and zeroes out/ok. K2 (6 blocks) gathers its ~M compact entries into regs,
// then runs the PROVEN R11 grid-build/NMS/rank/P5/P6 verbatim. Within-cell
// order stays arbitrary (already true in R11: atomic scatter); all
// suppression/tie-break arithmetic keys off pixel indices in cmb. Global
// k-means fallback replaced by rank-windowed multi-pass (sK>2048 only).
// ---------------------------------------------------------------------------

__global__ __launch_bounds__(KTHR) void k_front(
    const float* __restrict__ seg, const float* __restrict__ lidar,
    float* __restrict__ xs, float* __restrict__ ys,
    unsigned int* __restrict__ ns, unsigned int* __restrict__ counts,
    float* __restrict__ out)
{
    const int tid = threadIdx.x, lane = tid & 63;
    const int idx = blockIdx.x * KTHR + tid;       // [0, B*NPTS)
    const int b = idx >> 13, n = idx & 8191;

    __shared__ float ex[KTHR], ey[KTHR];
    __shared__ unsigned short en[KTHR];
    __shared__ unsigned int cnt6[6], off6[6], pos6[6];

    if (tid < 6) cnt6[tid] = 0;
    __syncthreads();

    // per-pixel argmax (strict >: first index wins ties)
    const float* segb = seg + (size_t)b * BCLS * NPTS + n;
    float bv = segb[0];
    int bc = 0;
    #pragma unroll
    for (int c = 1; c < BCLS; ++c) {
        float v = segb[(size_t)c * NPTS];
        if (v > bv) { bv = v; bc = c; }
    }
    const float x = lidar[(size_t)b * 2 * NPTS + n];
    const float y = lidar[(size_t)b * 2 * NPTS + NPTS + n];
    const int p = (bc > 0) ? (b * 3 + bc - 1) : -1;

    // phase A: wave-aggregated per-pair counts
    #pragma unroll
    for (int q = 0; q < 6; ++q) {
        unsigned long long bal = __ballot(p == q);
        if (lane == 0 && bal) atomicAdd(&cnt6[q], (unsigned int)__popcll(bal));
    }
    __syncthreads();
    if (tid == 0) {
        unsigned int a = 0;
        #pragma unroll
        for (int q = 0; q < 6; ++q) { off6[q] = a; pos6[q] = a; a += cnt6[q]; }
    }
    __syncthreads();
    // phase B: wave-aggregated placement into pair-grouped staging
    #pragma unroll
    for (int q = 0; q < 6; ++q) {
        unsigned long long bal = __ballot(p == q);
        if (bal) {
            int ldr = __builtin_ctzll(bal);
            unsigned int wb = 0;
            if (lane == ldr) wb = atomicAdd(&pos6[q], (unsigned int)__popcll(bal));
            wb = __shfl(wb, ldr, 64);
            if (p == q) {
                unsigned int s = wb + (unsigned int)__popcll(bal & ((1ull << lane) - 1ull));
                ex[s] = x; ey[s] = y; en[s] = (unsigned short)n;
            }
        }
    }
    __syncthreads();
    // flush grouped staging to this block's slab chunk + counts row
    {
        const unsigned int total = off6[5] + cnt6[5];
        const int gbase = blockIdx.x * KTHR;
        for (int k = tid; k < (int)total; k += KTHR) {
            xs[gbase + k] = ex[k];
            ys[gbase + k] = ey[k];
            ns[gbase + k] = (unsigned int)en[k];
        }
        if (tid < 6) counts[blockIdx.x * 6 + tid] = cnt6[tid];
    }
    // zero out+ok: (2*NP*NPTS + NP*NPTS) floats = 147456 = 36864 float4
    {
        float4* o4 = (float4*)out;
        for (int k = idx; k < 36864; k += KBLK * KTHR)
            o4[k] = make_float4(0.f, 0.f, 0.f, 0.f);
    }
}

__global__ __launch_bounds__(1024) void k_nms(
    const float* __restrict__ xs, const float* __restrict__ ys,
    const unsigned int* __restrict__ ns, const unsigned int* __restrict__ counts,
    float* __restrict__ out)
{
    const int p = blockIdx.x;
    const int tid = threadIdx.x, lane = tid & 63, wv = tid >> 6;
    const int base = p * NPTS;

    __shared__ float2 sps[NPTS];                // 64 KB: grid-space coords
    __shared__ unsigned int cmb[NPTS];          // 32 KB: pixel<<2 | status
    __shared__ unsigned int cellpack[NCELL];    // 16 KB: start<<16 | cnt
    __shared__ unsigned short plist[2][PCAP];   //  8 KB
    __shared__ float ksx[LDSK], ksy[LDSK], kcn[LDSK];  // 24 KB
    __shared__ int pcnt[2];
    __shared__ unsigned long long ballots[128]; // kept-rank words
    __shared__ unsigned int base128[128];
    __shared__ unsigned int wtot[16];
    __shared__ float redbuf[4][16];
    __shared__ unsigned int csrc[KBLK], cdst[KBLK], clen[KBLK];
    __shared__ float sbminx, sbminy, scell;
    __shared__ int sM, sK;

    float* ok = out + (size_t)2 * NP * NPTS + base;

    // ---- P0: zero LDS state (out/ok zeroed by k_front) ----
    for (int k = tid; k < NPTS; k += 1024) cmb[k] = ST_U;
    for (int k = tid; k < NCELL; k += 1024) cellpack[k] = 0u;
    for (int k = tid; k < LDSK; k += 1024) { ksx[k] = 0.f; ksy[k] = 0.f; kcn[k] = 0.f; }
    if (tid == 0) { pcnt[0] = 0; pcnt[1] = 0; }

    // ---- chunk table: lane k of wave 0 owns source block k ----
    if (wv == 0) {
        unsigned int c6[6];
        #pragma unroll
        for (int q = 0; q < 6; ++q) c6[q] = counts[lane * 6 + q];
        unsigned int within = 0;
        for (int q = 0; q < p; ++q) within += c6[q];
        unsigned int len = c6[p];
        unsigned int v = len;
        for (int d = 1; d < 64; d <<= 1) {
            unsigned int u = __shfl_up(v, d, 64);
            if (lane >= d) v += u;
        }
        csrc[lane] = lane * KTHR + within;
        cdst[lane] = v - len;
        clen[lane] = len;
        if (lane == 63) sM = (int)v;
    }
    __syncthreads();
    const int M = sM;

    // ---- gather compact entries into regs + bbox ----
    float xq[8], yq[8];
    unsigned int nq[8];
    int liq[8];
    {
        float mnx = 3e38f, mxx = -3e38f, mny = 3e38f, mxy = -3e38f;
        #pragma unroll
        for (int q = 0; q < 8; ++q) {
            int li = q * 1024 + tid;
            liq[q] = li;
            if (li < M) {
                int lo = 0, hi = KBLK - 1;          // last k with cdst[k] <= li
                #pragma unroll
                for (int s = 0; s < 6; ++s) {
                    int mid = (lo + hi + 1) >> 1;
                    if (cdst[mid] <= (unsigned int)li) lo = mid; else hi = mid - 1;
                }
                int si = csrc[lo] + (li - cdst[lo]);
                float x = xs[si], y = ys[si];
                xq[q] = x; yq[q] = y; nq[q] = ns[si];
                mnx = fminf(mnx, x); mxx = fmaxf(mxx, x);
                mny = fminf(mny, y); mxy = fmaxf(mxy, y);
            }
        }
        for (int d = 32; d; d >>= 1) {
            mnx = fminf(mnx, __shfl_xor(mnx, d, 64));
            mxx = fmaxf(mxx, __shfl_xor(mxx, d, 64));
            mny = fminf(mny, __shfl_xor(mny, d, 64));
            mxy = fmaxf(mxy, __shfl_xor(mxy, d, 64));
        }
        if (lane == 0) { redbuf[0][wv] = mnx; redbuf[1][wv] = mxx;
                         redbuf[2][wv] = mny; redbuf[3][wv] = mxy; }
    }
    __syncthreads();
    if (tid == 0) {
        float a = redbuf[0][0], b2 = redbuf[1][0], c = redbuf[2][0], d = redbuf[3][0];
        for (int q = 1; q < 16; ++q) {
            a = fminf(a, redbuf[0][q]); b2 = fmaxf(b2, redbuf[1][q]);
            c = fminf(c, redbuf[2][q]); d = fmaxf(d, redbuf[3][q]);
        }
        sbminx = a; sbminy = c;
        scell = fmaxf(2.0f * RAD, fmaxf(b2 - a, d - c) / 63.0f);
    }
    __syncthreads();
    const float bminx = sbminx, bminy = sbminy, inv = 1.0f / scell;

    // ---- grid count / scan / scatter (coords held in regs) ----
    int cellq[8];
    #pragma unroll
    for (int q = 0; q < 8; ++q) {
        if (liq[q] < M) {
            int ix = min(GRD - 1, max(0, (int)((xq[q] - bminx) * inv)));
            int iy = min(GRD - 1, max(0, (int)((yq[q] - bminy) * inv)));
            cellq[q] = iy * GRD + ix;
            atomicAdd(&cellpack[cellq[q]], 1u);
        } else cellq[q] = -1;
    }
    __syncthreads();
    {
        unsigned int c4[4], t4 = 0;
        #pragma unroll
        for (int q = 0; q < 4; ++q) { c4[q] = cellpack[tid * 4 + q]; t4 += c4[q]; }
        unsigned int v = t4;
        for (int d = 1; d < 64; d <<= 1) {
            unsigned int u = __shfl_up(v, d, 64);
            if (lane >= d) v += u;
        }
        if (lane == 63) wtot[wv] = v;
        __syncthreads();
        if (tid == 0) {
            unsigned int acc = 0;
            for (int q = 0; q < 16; ++q) { unsigned int t = wtot[q]; wtot[q] = acc; acc += t; }
        }
        __syncthreads();
        unsigned int excl = wtot[wv] + v - t4;
        #pragma unroll
        for (int q = 0; q < 4; ++q) { cellpack[tid * 4 + q] = excl << 16; excl += c4[q]; }
    }
    __syncthreads();
    #pragma unroll
    for (int q = 0; q < 8; ++q) {
        if (cellq[q] >= 0) {
            unsigned int old = atomicAdd(&cellpack[cellq[q]], 1u);
            unsigned int pos = (old >> 16) + (old & 0xffffu);
            sps[pos] = make_float2(xq[q], yq[q]);
            cmb[pos] = (nq[q] << 2) | ST_U;
        }
    }   // cellpack now = start<<16 | cnt; sps/cmb grid-space
    __syncthreads();

    // flat window row scan over two contiguous streams (branchless)
    #define ROW_FLAGS(CY, CX0, CX1, NI, ME, DEAD, UNDEC)                          \
    {                                                                             \
        unsigned int wa = cellpack[(CY) * GRD + (CX0)];                           \
        unsigned int wb = cellpack[(CY) * GRD + (CX1)];                           \
        unsigned int f0 = wa >> 16, f1 = (wb >> 16) + (wb & 0xffffu);             \
        for (unsigned int f = f0; f < f1; ++f) {                                  \
            unsigned int wf = cmb[f];                                             \
            float2 q = sps[f];                                                    \
            float dx = __fsub_rn((ME).x, q.x), dy = __fsub_rn((ME).y, q.y);       \
            float d2 = __fadd_rn(__fmul_rn(dx, dx), __fmul_rn(dy, dy));           \
            bool in = (d2 < R2) & ((int)(wf >> 2) < (NI));                        \
            DEAD  |= in & ((wf & 3u) == ST_A);                                    \
            UNDEC |= in & ((wf & 3u) == ST_U);                                    \
        }                                                                         \
    }
    #define SCAN_FLAGS(NI, ME, DEAD, UNDEC)                                       \
    {                                                                             \
        int cx0 = max(0, (int)(((ME).x - RAD - bminx) * inv));                    \
        int cx1 = min(GRD - 1, (int)(((ME).x + RAD - bminx) * inv));              \
        int cy0 = max(0, (int)(((ME).y - RAD - bminy) * inv));                    \
        int cy1 = min(GRD - 1, (int)(((ME).y + RAD - bminy) * inv));              \
        DEAD = false; UNDEC = false;                                              \
        ROW_FLAGS(cy0, cx0, cx1, NI, ME, DEAD, UNDEC);                            \
        if (cy1 > cy0) ROW_FLAGS(cy1, cx0, cx1, NI, ME, DEAD, UNDEC);             \
    }

    // ---- P4 round 0: full sweep (grid order), wave-ordered pending append ----
    for (int e = tid; e < M; e += 1024) {
        unsigned int w = cmb[e];
        int ni = (int)(w >> 2);
        float2 me = sps[e];
        bool dead, undec;
        SCAN_FLAGS(ni, me, dead, undec);
        if (dead) cmb[e] = (w & ~3u) | ST_D;
        else if (!undec) cmb[e] = (w & ~3u) | ST_A;
        bool pendf = !dead && undec;
        unsigned long long act = __ballot(true);
        unsigned long long bal = __ballot(pendf);
        int leader = __builtin_ctzll(act);
        int cnt = __popcll(bal);
        int wbase = 0;
        if (lane == leader && cnt) wbase = atomicAdd(&pcnt[0], cnt);
        wbase = __shfl(wbase, leader, 64);
        if (pendf) {
            int pos = wbase + __popcll(bal & ((1ull << lane) - 1ull));
            if (pos < PCAP) plist[0][pos] = (unsigned short)e;
        }
    }

    // ---- P4 rounds over compacted pending (proven engine) ----
    int cur = 0;
    for (int round = 0; round < NPTS; ++round) {
        __syncthreads();
        int pc = pcnt[cur];
        if (pc == 0) break;
        if (pc > PCAP) {                        // overflow fallback: full sweeps
            for (;;) {
                bool any = false;
                __syncthreads();
                for (int e = tid; e < M; e += 1024) {
                    unsigned int w = cmb[e];
                    if ((w & 3u) != ST_U) continue;
                    int ni = (int)(w >> 2);
                    float2 me = sps[e];
                    bool dead, undec;
                    SCAN_FLAGS(ni, me, dead, undec);
                    if (dead) cmb[e] = (w & ~3u) | ST_D;
                    else if (!undec) cmb[e] = (w & ~3u) | ST_A;
                    else any = true;
                }
                if (__syncthreads_count(any) == 0) break;
            }
            break;
        }
        if (tid == 0) pcnt[cur ^ 1] = 0;
        __syncthreads();
        for (int idx = tid; idx < pc; idx += 1024) {
            int e = plist[cur][idx];
            unsigned int w = cmb[e];
            int ni = (int)(w >> 2);
            float2 me = sps[e];
            bool dead, undec;
            SCAN_FLAGS(ni, me, dead, undec);
            if (dead) cmb[e] = (w & ~3u) | ST_D;
            else if (!undec) cmb[e] = (w & ~3u) | ST_A;
            bool pendf = !dead && undec;
            unsigned long long act = __ballot(true);
            unsigned long long bal = __ballot(pendf);
            int leader = __builtin_ctzll(act);
            int cnt = __popcll(bal);
            int wbase = 0;
            if (lane == leader && cnt) wbase = atomicAdd(&pcnt[cur ^ 1], cnt);
            wbase = __shfl(wbase, leader, 64);
            if (pendf) {
                int pos = wbase + __popcll(bal & ((1ull << lane) - 1ull));
                if (pos < PCAP) plist[cur ^ 1][pos] = (unsigned short)e;
            }
        }
        cur ^= 1;
    }
    __syncthreads();

    // ---- kept-rank over grid space: ballot bitmask + wave-scanned prefix ----
    for (int k = 0; k < 8; ++k) {
        int e = (k << 10) + tid;
        unsigned long long bal = __ballot((cmb[e] & 3u) == ST_A);  // e>=M stays U
        if (lane == 0) ballots[(k << 4) + wv] = bal;
    }
    __syncthreads();
    if (wv == 0) {
        unsigned int p0 = (unsigned int)__popcll(ballots[2 * lane]);
        unsigned int p1 = (unsigned int)__popcll(ballots[2 * lane + 1]);
        unsigned int s = p0 + p1, v = s;
        for (int d = 1; d < 64; d <<= 1) {
            unsigned int u = __shfl_up(v, d, 64);
            if (lane >= d) v += u;
        }
        base128[2 * lane] = v - s;
        base128[2 * lane + 1] = v - p1;
        if (lane == 63) sK = (int)v;
    }
    __syncthreads();
    #define KRANK(E) ((int)base128[(E) >> 6] +                                    \
                      __popcll(ballots[(E) >> 6] & ((1ull << ((E) & 63)) - 1ull)))

    // ---- P5+P6: rank-windowed passes (1 pass when sK <= LDSK: the norm) ----
    #define ROW_ARGMIN(CY, CX0, CX1, ME, BD, BE, BN)                              \
    {                                                                             \
        unsigned int wa = cellpack[(CY) * GRD + (CX0)];                           \
        unsigned int wb = cellpack[(CY) * GRD + (CX1)];                           \
        unsigned int f0 = wa >> 16, f1 = (wb >> 16) + (wb & 0xffffu);             \
        for (unsigned int f = f0; f < f1; ++f) {                                  \
            unsigned int wf = cmb[f];                                             \
            float2 q = sps[f];                                                    \
            float dx = __fsub_rn((ME).x, q.x), dy = __fsub_rn((ME).y, q.y);       \
            float d2 = __fadd_rn(__fmul_rn(dx, dx), __fmul_rn(dy, dy));           \
            int nf = (int)(wf >> 2);                                              \
            bool better = ((wf & 3u) == ST_A) &                                   \
                          ((d2 < BD) | ((d2 == BD) & (nf < BN)));                 \
            BD = better ? d2 : BD;                                                \
            BE = better ? (int)f : BE;                                            \
            BN = better ? nf : BN;                                                \
        }                                                                         \
    }
    const int npass = (sK + LDSK - 1) / LDSK;
    for (int pass = 0; pass < npass; ++pass) {
        const int rb = pass * LDSK;
        if (pass) {
            __syncthreads();
            for (int k = tid; k < LDSK; k += 1024) { ksx[k] = 0.f; ksy[k] = 0.f; kcn[k] = 0.f; }
        }
        __syncthreads();
        for (int e = tid; e < M; e += 1024) {
            unsigned int w = cmb[e];
            float2 me = sps[e];
            int be;
            if ((w & 3u) == ST_A) {
                be = e;                          // self: unique d2 = 0
            } else {
                int cx0 = max(0, (int)((me.x - RAD - bminx) * inv));
                int cx1 = min(GRD - 1, (int)((me.x + RAD - bminx) * inv));
                int cy0 = max(0, (int)((me.y - RAD - bminy) * inv));
                int cy1 = min(GRD - 1, (int)((me.y + RAD - bminy) * inv));
                float bd = 3e38f;
                be = -1;
                int bn = 1 << 30;
                ROW_ARGMIN(cy0, cx0, cx1, me, bd, be, bn);
                if (cy1 > cy0) ROW_ARGMIN(cy1, cx0, cx1, me, bd, be, bn);
                if (be < 0) continue;            // impossible when M > 0
            }
            int r = KRANK(be) - rb;
            if (r >= 0 && r < LDSK) {
                atomicAdd(&ksx[r], me.x);
                atomicAdd(&ksy[r], me.y);
                atomicAdd(&kcn[r], 1.0f);
            }
        }
        __syncthreads();
        for (int e = tid; e < M; e += 1024) {
            unsigned int w = cmb[e];
            if ((w & 3u) != ST_A) continue;
            int r = KRANK(e) - rb;
            if (r < 0 || r >= LDSK) continue;
            int n = (int)(w >> 2);
            float sx = ksx[r], sy = ksy[r], c = kcn[r];
            out[2 * (base + n)]     = sx / c;    // c >= 1 (self-assign)
            out[2 * (base + n) + 1] = sy / c;
            ok[n] = 1.0f;
        }
    }
}

// ---------------------------------------------------------------------------
extern "C" void kernel_launch(void* const* d_in, const int* in_sizes, int n_in,
                              void* d_out, int out_size, void* d_ws, size_t ws_size,
                              hipStream_t stream) {
    const float* seg   = (const float*)d_in[0];   // [B,C,H,W] f32
    const float* lidar = (const float*)d_in[1];   // [B,2,H,W] f32
    float* out = (float*)d_out;

    float* xs = (float*)d_ws;                     // 16384 f
    float* ys = xs + KBLK * KTHR;                 // 16384 f
    unsigned int* ns = (unsigned int*)(ys + KBLK * KTHR);   // 16384 u32
    unsigned int* counts = ns + KBLK * KTHR;      // KBLK*6 u32

    k_front<<<KBLK, KTHR, 0, stream>>>(seg, lidar, xs, ys, ns, counts, out);
    k_nms<<<NP, 1024, 0, stream>>>(xs, ys, ns, counts, out);
}